// Round 5
// baseline (327.236 us; speedup 1.0000x reference)
//
#include <hip/hip_runtime.h>

// OrthogonalAddTSU: sequential scan over S steps, carry h:(B,H).
// Per step: cos = <h,s>/max(|h||s|,eps); h = clip(h + (s - h*cos)*m, -1, 1).
// B=64, H=1024, S=512.
//
// Round-5 structure: 4 waves per batch (64 blocks x 256 threads), H split
// 256 elems/wave, 4 elems/lane. Rationale: round 4 proved the kernel is
// serial-chain latency-bound on one lone wave/CU (pipelining memory gained
// only 4%; VALUBusy 51% of the single active SIMD). 4 waves put 4 SIMDs on
// the chain and cut per-wave elementwise work 4x.
//  - Per step: each wave reduces (dot,|h|^2,|s|^2) over its 64 lanes via a
//    3-chain interleaved DPP butterfly (totals in lane 63, no readlane),
//    lane 63 writes one float4 to LDS, ONE s_barrier, all lanes broadcast-
//    read the 4 partials, combine, cos is lane-uniform.
//  - LDS slots are parity double-buffered, parity toggled per EXECUTED step
//    (skipped steps toggle nothing) -> single barrier per step is race-free.
//  - Global loads remain volatile-asm ping-pong (4 x dwordx4 per group,
//    s_waitcnt vmcnt(4) operand-tied). Barrier is raw asm
//    "s_waitcnt lgkmcnt(0); s_barrier" + memory clobber: the compiler
//    tracks no VMEM loads, so no vmcnt(0) drain is emitted at the barrier
//    (which would serialize the prefetch).
//  - mask binary: m==0 steps skipped block-uniformly (h already clipped =>
//    unchanged; t==0 still needs the clip).

#define NB 64
#define NH 1024
#define NS 512

typedef float v4f __attribute__((ext_vector_type(4)));

template <int CTRL>
__device__ __forceinline__ float dpp_add(float x) {
  int s = __builtin_amdgcn_update_dpp(0, __builtin_bit_cast(int, x), CTRL, 0xf,
                                      0xf, true);
  return x + __builtin_bit_cast(float, s);
}

__device__ __forceinline__ float readlane_f(float v, int lane) {
  return __builtin_bit_cast(
      float, __builtin_amdgcn_readlane(__builtin_bit_cast(int, v), lane));
}

// 3 interleaved 64-lane butterfly chains; totals land in lane 63 only.
__device__ __forceinline__ void wave_red3_l63(float& a, float& b, float& c) {
  a = dpp_add<0x111>(a); b = dpp_add<0x111>(b); c = dpp_add<0x111>(c);
  a = dpp_add<0x112>(a); b = dpp_add<0x112>(b); c = dpp_add<0x112>(c);
  a = dpp_add<0x114>(a); b = dpp_add<0x114>(b); c = dpp_add<0x114>(c);
  a = dpp_add<0x118>(a); b = dpp_add<0x118>(b); c = dpp_add<0x118>(c);
  a = dpp_add<0x142>(a); b = dpp_add<0x142>(b); c = dpp_add<0x142>(c);
  a = dpp_add<0x143>(a); b = dpp_add<0x143>(b); c = dpp_add<0x143>(c);
}

// volatile asm loads: cannot be sunk/reordered vs other volatile asm.
#define GLD4(dst, p, OFFSTR)                                   \
  asm volatile("global_load_dwordx4 %0, %1, off" OFFSTR        \
               : "=v"(dst)                                     \
               : "v"(p))
#define GLD1(dst, p)                                           \
  asm volatile("global_load_dword %0, %1, off" : "=v"(dst) : "v"(p))

// One group = this lane's 4 rows x 4 steps (16B each). Pointer is biased
// +2 rows so offsets fit the 13-bit signed imm: -4096,-2048,0,+2048.
#define ISSUE4(buf)                        \
  do {                                     \
    GLD4(buf[0], pr, " offset:-4096");     \
    GLD4(buf[1], pr, " offset:-2048");     \
    GLD4(buf[2], pr, "");                  \
    GLD4(buf[3], pr, " offset:2048");      \
    pr += 4;                               \
  } while (0)

// Wait until <=N VMEM loads outstanding; tie buffer regs so later uses are
// data-dependent on the wait.
#define WAITPIN4(buf, N)                                       \
  asm volatile("s_waitcnt vmcnt(" N ")"                        \
               : "+v"(buf[0]), "+v"(buf[1]), "+v"(buf[2]),     \
                 "+v"(buf[3]))

// lgkm drain (lane-63 ds_write committed) + workgroup barrier. Memory
// clobber keeps compiler LDS ops on their side of the barrier.
#define XBARRIER() \
  asm volatile("s_waitcnt lgkmcnt(0)\n\ts_barrier" ::: "memory")

__global__ __launch_bounds__(256, 1) void otsu_scan_kernel(
    const float* __restrict__ tree,   // (B,H)
    const float* __restrict__ seq,    // (B,H,S)
    const float* __restrict__ mask,   // (B,S)
    float* __restrict__ out) {        // (B,H)
  const int b = blockIdx.x;
  const int tid = threadIdx.x;
  const int w = tid >> 6;    // wave 0..3, owns H-chunk [256w, 256w+256)
  const int lane = tid & 63; // owns 4 rows: 256w + 4*lane .. +3

  __shared__ v4f xch[2][4];  // [parity][wave] = (dot, hh, ss, pad) partials
  __shared__ v4f dump[4];    // write target for lanes != 63

  // --- initial h (one dwordx4/lane) and masks, all via asm + full drain ---
  const float* hrow = tree + b * NH + w * 256 + lane * 4;
  v4f hv;
  GLD4(hv, hrow, "");
  float m8[8];
  {
    const float* mp = mask + b * NS + lane;  // same for all 4 waves
    GLD1(m8[0], mp);
    GLD1(m8[1], mp + 64);
    GLD1(m8[2], mp + 128);
    GLD1(m8[3], mp + 192);
    GLD1(m8[4], mp + 256);
    GLD1(m8[5], mp + 320);
    GLD1(m8[6], mp + 384);
    GLD1(m8[7], mp + 448);
  }
  asm volatile("s_waitcnt vmcnt(0)"
               : "+v"(hv), "+v"(m8[0]), "+v"(m8[1]), "+v"(m8[2]),
                 "+v"(m8[3]), "+v"(m8[4]), "+v"(m8[5]), "+v"(m8[6]),
                 "+v"(m8[7]));

  float h[4] = {hv.x, hv.y, hv.z, hv.w};

  // seq pointer for this lane's 4 rows, biased +2 rows (see ISSUE4)
  const float* pr =
      seq + (size_t)b * NH * NS + (size_t)(w * 256 + lane * 4 + 2) * NS;

  v4f bufA[4], bufB[4];
  int p = 0;  // LDS parity, toggled per EXECUTED step

  // Process one 4-step group. lbase = (t & 63) of the group's first step.
  auto process4 = [&](const v4f* buf, float mv, int lbase, bool has_t0) {
#pragma unroll
    for (int j = 0; j < 4; ++j) {
      const float m = readlane_f(mv, lbase + j);  // block-uniform
      if (m != 0.0f) {
        const float s0 = buf[0][j], s1 = buf[1][j];
        const float s2 = buf[2][j], s3 = buf[3][j];
        // per-lane partials over 4 elems (2 chains + add each)
        float d = fmaf(h[0], s0, h[1] * s1) + fmaf(h[2], s2, h[3] * s3);
        float e = fmaf(h[0], h[0], h[1] * h[1]) +
                  fmaf(h[2], h[2], h[3] * h[3]);
        float f = fmaf(s0, s0, s1 * s1) + fmaf(s2, s2, s3 * s3);
        wave_red3_l63(d, e, f);  // totals in lane 63
        v4f val = {d, e, f, 0.0f};
        v4f* dst = (lane == 63) ? &xch[p][w] : &dump[w];
        *dst = val;          // one ds_write_b128 (cndmask'd address)
        XBARRIER();          // lgkmcnt(0) + s_barrier (no vmcnt drain)
        v4f r0 = xch[p][0];  // broadcast reads: same addr across lanes
        v4f r1 = xch[p][1];
        v4f r2 = xch[p][2];
        v4f r3 = xch[p][3];
        v4f tt = (r0 + r1) + (r2 + r3);
        const float pp = fmaxf(tt.y * tt.z, 1e-16f);  // denom^2, eps=1e-8
        const float c = tt.x * __builtin_amdgcn_rsqf(pp);
        const float a = 1.0f - c;  // m==1: h_new = clip(h*(1-c) + s)
        h[0] = __builtin_amdgcn_fmed3f(fmaf(h[0], a, s0), -1.0f, 1.0f);
        h[1] = __builtin_amdgcn_fmed3f(fmaf(h[1], a, s1), -1.0f, 1.0f);
        h[2] = __builtin_amdgcn_fmed3f(fmaf(h[2], a, s2), -1.0f, 1.0f);
        h[3] = __builtin_amdgcn_fmed3f(fmaf(h[3], a, s3), -1.0f, 1.0f);
        p ^= 1;
      } else if (has_t0 && j == 0) {
        // t==0, m==0: clip still applies; no barrier (block-uniform skip)
#pragma unroll
        for (int i = 0; i < 4; ++i)
          h[i] = __builtin_amdgcn_fmed3f(h[i], -1.0f, 1.0f);
      }
      // m==0, t>0: h already clipped -> unchanged, skip (block-uniform).
    }
  };

  ISSUE4(bufA);  // group 0

  // 8 supergroups (64 steps each). sg<7: 8 iters x 2 groups; sg==7: 7 iters
  // + explicit 2-group tail (avoids issuing OOB group 128).
#pragma unroll
  for (int sg = 0; sg < 8; ++sg) {
    const float mv = m8[sg];
    const int nIter = (sg == 7) ? 7 : 8;
    for (int it = 0; it < nIter; ++it) {
      const int lbase = 8 * it;
      ISSUE4(bufB);          // group g+1
      WAITPIN4(bufA, "4");   // g's 4 done (4 newest outstanding = B's)
      process4(bufA, mv, lbase, sg == 0 && it == 0);
      ISSUE4(bufA);          // group g+2
      WAITPIN4(bufB, "4");
      process4(bufB, mv, lbase + 4, false);
    }
  }
  {  // tail: groups 126 (A) and 127 (B) = steps 504..511
    const float mv = m8[7];
    ISSUE4(bufB);  // group 127 (last issue; pr ends exactly at row end)
    WAITPIN4(bufA, "4");
    process4(bufA, mv, 56, false);
    WAITPIN4(bufB, "0");
    process4(bufB, mv, 60, false);
  }

  // --- write final h ---
  float* orow = out + b * NH + w * 256 + lane * 4;
  v4f hvout = {h[0], h[1], h[2], h[3]};
  *(v4f*)orow = hvout;
}

extern "C" void kernel_launch(void* const* d_in, const int* in_sizes, int n_in,
                              void* d_out, int out_size, void* d_ws,
                              size_t ws_size, hipStream_t stream) {
  const float* tree = (const float*)d_in[0];  // (64,1024)
  const float* seq = (const float*)d_in[1];   // (64,1024,512)
  const float* mask = (const float*)d_in[2];  // (64,512)
  float* out = (float*)d_out;                 // (64,1024)
  otsu_scan_kernel<<<dim3(NB), dim3(256), 0, stream>>>(tree, seq, mask, out);
}

// Round 7
// 315.350 us; speedup vs baseline: 1.0377x; 1.0377x over previous
//
#include <hip/hip_runtime.h>

// OrthogonalAddTSU: sequential scan over S steps, carry h:(B,H).
// Per step: cos = <h,s>/max(|h||s|,eps); h = clip(h + (s - h*cos)*m, -1, 1).
// B=64, H=1024, S=512. One wave per batch; 16 h-elements per lane.
//
// Round-7 = round-6 (small rolled hot loop, I$ theory) + writelane fix:
//  __builtin_amdgcn_writelane is not declared on this ROCm; build the
//  packed-mask VGPRs with (lane==k) ? w : v selects instead (one-time).
//
//  - R1-R5 unrolled the supergroup loop x8 (forced by register-array
//    m8[sg] indexing) -> 30-70 KB straight-line bodies thrashing the 32 KB
//    L1I every iteration; explains uniform ~175-330 us across different
//    memory/exchange structures and chip VALUBusy pinned ~3%.
//  - Main loop rolled to 63 iterations (ping-pong pair of 4-step groups),
//    unroll(disable) enforced; body ~10 KB, fits L1I.
//  - Mask bit-packed: ballot each 64-step supergroup's mask into a u64,
//    select words into lanes of 2 VGPRs at start; per iter 2 dynamic
//    readlanes rebuild the word in SGPRs; per STEP the mask is SALU
//    (s_lshr_b64 + cselect) -> no per-step v_readlane, no branch.
//  - Branchless step: a = fma(-c, m, 1); h = med3(fma(h, a, s*m), -1, 1).
//    m==0 => h = med3(h) = h (h already in [-1,1]); subsumes the t==0
//    clip-on-masked-step case. No skip logic.
//  - Layout = round-4 (fastest so far): 1 wave/batch, 16 elem/lane, no LDS.
//    Global loads volatile-asm ping-pong (16 x dwordx4 per group,
//    s_waitcnt vmcnt(16) operand-tied); no compiler-tracked VMEM anywhere.

#define NB 64
#define NH 1024
#define NS 512
#define EL 16

typedef float v4f __attribute__((ext_vector_type(4)));

template <int CTRL>
__device__ __forceinline__ float dpp_add(float x) {
  int s = __builtin_amdgcn_update_dpp(0, __builtin_bit_cast(int, x), CTRL, 0xf,
                                      0xf, true);
  return x + __builtin_bit_cast(float, s);
}

__device__ __forceinline__ float readlane_f(float v, int lane) {
  return __builtin_bit_cast(
      float, __builtin_amdgcn_readlane(__builtin_bit_cast(int, v), lane));
}

__device__ __forceinline__ void wave_sum2(float& a, float& b) {
  a = dpp_add<0x111>(a); b = dpp_add<0x111>(b);
  a = dpp_add<0x112>(a); b = dpp_add<0x112>(b);
  a = dpp_add<0x114>(a); b = dpp_add<0x114>(b);
  a = dpp_add<0x118>(a); b = dpp_add<0x118>(b);
  a = dpp_add<0x142>(a); b = dpp_add<0x142>(b);
  a = dpp_add<0x143>(a); b = dpp_add<0x143>(b);
  a = readlane_f(a, 63);
  b = readlane_f(b, 63);
}

__device__ __forceinline__ void wave_sum4(float& a, float& b, float& c,
                                          float& d) {
  a = dpp_add<0x111>(a); b = dpp_add<0x111>(b); c = dpp_add<0x111>(c); d = dpp_add<0x111>(d);
  a = dpp_add<0x112>(a); b = dpp_add<0x112>(b); c = dpp_add<0x112>(c); d = dpp_add<0x112>(d);
  a = dpp_add<0x114>(a); b = dpp_add<0x114>(b); c = dpp_add<0x114>(c); d = dpp_add<0x114>(d);
  a = dpp_add<0x118>(a); b = dpp_add<0x118>(b); c = dpp_add<0x118>(c); d = dpp_add<0x118>(d);
  a = dpp_add<0x142>(a); b = dpp_add<0x142>(b); c = dpp_add<0x142>(c); d = dpp_add<0x142>(d);
  a = dpp_add<0x143>(a); b = dpp_add<0x143>(b); c = dpp_add<0x143>(c); d = dpp_add<0x143>(d);
  a = readlane_f(a, 63);
  b = readlane_f(b, 63);
  c = readlane_f(c, 63);
  d = readlane_f(d, 63);
}

// volatile asm loads: cannot be sunk/reordered vs other volatile asm.
#define GLD4(dst, p, OFFSTR)                                   \
  asm volatile("global_load_dwordx4 %0, %1, off" OFFSTR        \
               : "=v"(dst)                                     \
               : "v"(p))
#define GLD1(dst, p)                                           \
  asm volatile("global_load_dword %0, %1, off" : "=v"(dst) : "v"(p))

// Issue one group (16 rows x 16B) and advance the 4 row-base pointers.
// Pointers biased +4096 B: rows at 13-bit-signed offsets -4096..+2048.
#define ISSUE16(buf)                       \
  do {                                     \
    GLD4(buf[0], p0, " offset:-4096");     \
    GLD4(buf[1], p0, " offset:-2048");     \
    GLD4(buf[2], p0, "");                  \
    GLD4(buf[3], p0, " offset:2048");      \
    GLD4(buf[4], p1, " offset:-4096");     \
    GLD4(buf[5], p1, " offset:-2048");     \
    GLD4(buf[6], p1, "");                  \
    GLD4(buf[7], p1, " offset:2048");      \
    GLD4(buf[8], p2, " offset:-4096");     \
    GLD4(buf[9], p2, " offset:-2048");     \
    GLD4(buf[10], p2, "");                 \
    GLD4(buf[11], p2, " offset:2048");     \
    GLD4(buf[12], p3, " offset:-4096");    \
    GLD4(buf[13], p3, " offset:-2048");    \
    GLD4(buf[14], p3, "");                 \
    GLD4(buf[15], p3, " offset:2048");     \
    p0 += 4; p1 += 4; p2 += 4; p3 += 4;    \
  } while (0)

// Wait until <=N VMEM loads outstanding; tie buffer regs so later uses are
// data-dependent on the wait (loads retire in issue order).
#define WAITPIN(buf, N)                                             \
  do {                                                              \
    asm volatile("s_waitcnt vmcnt(" N ")"                           \
                 : "+v"(buf[0]), "+v"(buf[1]), "+v"(buf[2]),        \
                   "+v"(buf[3]), "+v"(buf[4]), "+v"(buf[5]),        \
                   "+v"(buf[6]), "+v"(buf[7]));                     \
    asm volatile("s_waitcnt vmcnt(" N ")"                           \
                 : "+v"(buf[8]), "+v"(buf[9]), "+v"(buf[10]),       \
                   "+v"(buf[11]), "+v"(buf[12]), "+v"(buf[13]),     \
                   "+v"(buf[14]), "+v"(buf[15]));                   \
  } while (0)

__global__ __launch_bounds__(64, 1) void otsu_scan_kernel(
    const float* __restrict__ tree,   // (B,H)
    const float* __restrict__ seq,    // (B,H,S)
    const float* __restrict__ mask,   // (B,S)
    float* __restrict__ out) {        // (B,H)
  const int b = blockIdx.x;
  const int lane = threadIdx.x;  // 0..63

  // --- h + masks via asm loads + one full drain (no compiler VMEM) ---
  const float* hrow = tree + b * NH + lane * EL;
  v4f hv[4];
  GLD4(hv[0], hrow, "");
  GLD4(hv[1], hrow, " offset:16");
  GLD4(hv[2], hrow, " offset:32");
  GLD4(hv[3], hrow, " offset:48");
  float m8[8];
  {
    const float* mp = mask + b * NS + lane;
    GLD1(m8[0], mp);
    GLD1(m8[1], mp + 64);
    GLD1(m8[2], mp + 128);
    GLD1(m8[3], mp + 192);
    GLD1(m8[4], mp + 256);
    GLD1(m8[5], mp + 320);
    GLD1(m8[6], mp + 384);
    GLD1(m8[7], mp + 448);
  }
  asm volatile("s_waitcnt vmcnt(0)"
               : "+v"(hv[0]), "+v"(hv[1]), "+v"(hv[2]), "+v"(hv[3]),
                 "+v"(m8[0]), "+v"(m8[1]), "+v"(m8[2]), "+v"(m8[3]),
                 "+v"(m8[4]), "+v"(m8[5]), "+v"(m8[6]), "+v"(m8[7]));

  float h[EL];
#pragma unroll
  for (int k = 0; k < 4; ++k) {
    h[4 * k + 0] = hv[k].x;
    h[4 * k + 1] = hv[k].y;
    h[4 * k + 2] = hv[k].z;
    h[4 * k + 3] = hv[k].w;
  }

  // --- bit-pack masks: word k (supergroup k) into lane k of vlo/vhi.
  //     ballot result is wave-uniform (SGPR pair); (lane==k)?w:v compiles
  //     to v_cmp + v_cndmask (writelane builtin unavailable). ---
  int vlo = 0, vhi = 0;
#pragma unroll
  for (int k = 0; k < 8; ++k) {
    unsigned long long w = __ballot(m8[k] != 0.0f);
    vlo = (lane == k) ? (int)(unsigned)(w & 0xffffffffull) : vlo;
    vhi = (lane == k) ? (int)(unsigned)(w >> 32) : vhi;
  }

  // seq row-base pointers for this lane, biased +2 rows (see ISSUE16)
  const float* srow = seq + (size_t)b * NH * NS + (size_t)(lane * EL) * NS;
  const float* p0 = srow + 2 * NS;
  const float* p1 = srow + 6 * NS;
  const float* p2 = srow + 10 * NS;
  const float* p3 = srow + 14 * NS;

  v4f bufA[16], bufB[16];

  // One ping-pong half: 4 branchless steps from buf. bitbase = bit index of
  // step j=0 within mask word mw. All mask math is wave-uniform SALU.
  auto process4 = [&](const v4f* buf, unsigned long long mw, int bitbase) {
    // batched |s|^2 for the 4 steps: 4 interleaved DPP chains
    float fA0 = 0.f, fA1 = 0.f, fA2 = 0.f, fA3 = 0.f;
    float fB0 = 0.f, fB1 = 0.f, fB2 = 0.f, fB3 = 0.f;
#pragma unroll
    for (int i = 0; i < EL; i += 2) {
      fA0 = fmaf(buf[i][0], buf[i][0], fA0);
      fA1 = fmaf(buf[i][1], buf[i][1], fA1);
      fA2 = fmaf(buf[i][2], buf[i][2], fA2);
      fA3 = fmaf(buf[i][3], buf[i][3], fA3);
      fB0 = fmaf(buf[i + 1][0], buf[i + 1][0], fB0);
      fB1 = fmaf(buf[i + 1][1], buf[i + 1][1], fB1);
      fB2 = fmaf(buf[i + 1][2], buf[i + 1][2], fB2);
      fB3 = fmaf(buf[i + 1][3], buf[i + 1][3], fB3);
    }
    float s2g[4];
    s2g[0] = fA0 + fB0;
    s2g[1] = fA1 + fB1;
    s2g[2] = fA2 + fB2;
    s2g[3] = fA3 + fB3;
    wave_sum4(s2g[0], s2g[1], s2g[2], s2g[3]);

#pragma unroll
    for (int j = 0; j < 4; ++j) {
      // wave-uniform mask as float via SALU select (no readlane, no branch)
      const float m = ((mw >> (bitbase + j)) & 1ull) ? 1.0f : 0.0f;
      float d0 = 0.f, d1 = 0.f, d2 = 0.f, d3 = 0.f;
      float e0 = 0.f, e1 = 0.f, e2 = 0.f, e3 = 0.f;
#pragma unroll
      for (int i = 0; i < EL; i += 4) {
        const float sA = buf[i + 0][j];
        const float sB = buf[i + 1][j];
        const float sC = buf[i + 2][j];
        const float sD = buf[i + 3][j];
        d0 = fmaf(h[i + 0], sA, d0);
        e0 = fmaf(h[i + 0], h[i + 0], e0);
        d1 = fmaf(h[i + 1], sB, d1);
        e1 = fmaf(h[i + 1], h[i + 1], e1);
        d2 = fmaf(h[i + 2], sC, d2);
        e2 = fmaf(h[i + 2], h[i + 2], e2);
        d3 = fmaf(h[i + 3], sD, d3);
        e3 = fmaf(h[i + 3], h[i + 3], e3);
      }
      float dot = (d0 + d1) + (d2 + d3);
      float hh = (e0 + e1) + (e2 + e3);
      wave_sum2(dot, hh);
      const float pp = fmaxf(hh * s2g[j], 1e-16f);  // denom^2 (eps 1e-8)
      const float c = dot * __builtin_amdgcn_rsqf(pp);
      const float a = fmaf(-c, m, 1.0f);  // m==0 -> a=1
#pragma unroll
      for (int i = 0; i < EL; ++i) {
        const float sm = buf[i][j] * m;  // m==0 -> 0
        h[i] = __builtin_amdgcn_fmed3f(fmaf(h[i], a, sm), -1.0f, 1.0f);
      }
    }
  };

  ISSUE16(bufA);  // group 0

  // ROLLED main loop: 63 iters x 2 groups (8 steps). Body ~10 KB -> fits
  // L1I. Mask word rebuilt each iter from vlo/vhi via 2 dynamic readlanes.
#pragma clang loop unroll(disable)
  for (int it = 0; it < 63; ++it) {
    const int sg = it >> 3;
    const unsigned int wlo = (unsigned)__builtin_amdgcn_readlane(vlo, sg);
    const unsigned int whi = (unsigned)__builtin_amdgcn_readlane(vhi, sg);
    const unsigned long long mw = ((unsigned long long)whi << 32) | wlo;
    const int bitbase = (it & 7) * 8;
    ISSUE16(bufB);        // group 2it+1
    WAITPIN(bufA, "16");  // group 2it done (16 newest = B's)
    process4(bufA, mw, bitbase);
    ISSUE16(bufA);        // group 2it+2 (<= 126)
    WAITPIN(bufB, "16");
    process4(bufB, mw, bitbase + 4);
  }
  {  // tail: it=63 -> groups 126 (A) and 127 (B) = steps 504..511
    const unsigned int wlo = (unsigned)__builtin_amdgcn_readlane(vlo, 7);
    const unsigned int whi = (unsigned)__builtin_amdgcn_readlane(vhi, 7);
    const unsigned long long mw = ((unsigned long long)whi << 32) | wlo;
    ISSUE16(bufB);  // group 127 (last; pointers end exactly at row end)
    WAITPIN(bufA, "16");
    process4(bufA, mw, 56);
    WAITPIN(bufB, "0");
    process4(bufB, mw, 60);
  }

  // --- write final h ---
  float* orow = out + b * NH + lane * EL;
#pragma unroll
  for (int i = 0; i < EL / 4; ++i) {
    float4 v;
    v.x = h[4 * i + 0];
    v.y = h[4 * i + 1];
    v.z = h[4 * i + 2];
    v.w = h[4 * i + 3];
    *(float4*)(orow + 4 * i) = v;
  }
}

extern "C" void kernel_launch(void* const* d_in, const int* in_sizes, int n_in,
                              void* d_out, int out_size, void* d_ws,
                              size_t ws_size, hipStream_t stream) {
  const float* tree = (const float*)d_in[0];  // (64,1024)
  const float* seq = (const float*)d_in[1];   // (64,1024,512)
  const float* mask = (const float*)d_in[2];  // (64,512)
  float* out = (float*)d_out;                 // (64,1024)
  otsu_scan_kernel<<<dim3(NB), dim3(64), 0, stream>>>(tree, seq, mask, out);
}